// Round 20
// baseline (2280.462 us; speedup 1.0000x reference)
//
#include <hip/hip_runtime.h>
#include <stdint.h>
#include <stddef.h>

#define C_DIM 1024
#define T_DIM 1024
#define B_DIM 4
#define L_DIM 8
#define V_DIM 32000
#define HS 64
#define NHEAD 16
#define NROWS (B_DIM * T_DIM)   // 4096
#define LDQ   3072              // packed qkv row stride

typedef __bf16 bf16_t;
typedef __attribute__((ext_vector_type(8))) __bf16 bf16x8;
typedef __attribute__((ext_vector_type(4))) __bf16 bf16x4;
typedef __attribute__((ext_vector_type(4))) float f32x4;
typedef unsigned int u32;
typedef unsigned short u16;

static __device__ __forceinline__ f32x4 mfma16(bf16x8 a, bf16x8 b, f32x4 c) {
    return __builtin_amdgcn_mfma_f32_16x16x32_bf16(a, b, c, 0, 0, 0);
}

// async global->LDS, 16B per lane. LDS dest must be wave-uniform.
static __device__ __forceinline__ void gl_lds16(const bf16_t* g, bf16_t* l) {
    __builtin_amdgcn_global_load_lds(
        (const __attribute__((address_space(1))) u32*)(const void*)g,
        (__attribute__((address_space(3))) u32*)(void*)l, 16, 0, 0);
}

// ---------------------------------------------------------------------------
// Embedding
// ---------------------------------------------------------------------------
__global__ __launch_bounds__(256) void embed_kernel(
    const int* __restrict__ x, const float* __restrict__ tok,
    const float* __restrict__ pos, float* __restrict__ h) {
    int idx = blockIdx.x * 256 + threadIdx.x;
    int row = idx >> 8;
    int c4  = (idx & 255) * 4;
    int t   = row & (T_DIM - 1);
    int tk  = x[row];
    float4 a = *(const float4*)(tok + (size_t)tk * C_DIM + c4);
    float4 p = *(const float4*)(pos + (size_t)t * C_DIM + c4);
    float4 r;
    r.x = a.x + p.x; r.y = a.y + p.y; r.z = a.z + p.z; r.w = a.w + p.w;
    *(float4*)(h + (size_t)row * C_DIM + c4) = r;
}

// ---------------------------------------------------------------------------
// Weight convert+transpose 64x64 tile body:  f32 [K][N] -> bf16 [N][K]
// ---------------------------------------------------------------------------
static __device__ __forceinline__ void wtr_tile(
    const float* __restrict__ in, bf16_t* __restrict__ out,
    int K, int N, int n0, int k0, int tid) {
    __shared__ float t[64][65];
    int tx = tid & 63, tw = tid >> 6;
#pragma unroll 4
    for (int i = 0; i < 16; ++i) {
        int k = tw * 16 + i;
        t[k][tx] = in[(size_t)(k0 + k) * N + n0 + tx];
    }
    __syncthreads();
#pragma unroll 4
    for (int i = 0; i < 16; ++i) {
        int n = tw * 16 + i;
        out[(size_t)(n0 + n) * K + k0 + tx] = (bf16_t)t[tx][n];
    }
}

// ---------------------------------------------------------------------------
// Fused LayerNorm (blocks 0..1023) + per-layer weight conversion
// (1024..4095) + OPTIONAL head conversion (blocks >= 4096, layer 7 only).
// All pure streaming; conversions complete before the next kernel's reads.
// ---------------------------------------------------------------------------
__global__ __launch_bounds__(256) void ln_wtr_kernel(
    const float* __restrict__ x, const float* __restrict__ gam,
    const float* __restrict__ bet, bf16_t* __restrict__ out,
    const float* __restrict__ Wq, const float* __restrict__ Wk,
    const float* __restrict__ Wv, const float* __restrict__ Wp,
    const float* __restrict__ W1, const float* __restrict__ W2,
    bf16_t* __restrict__ qkvT, bf16_t* __restrict__ projT,
    bf16_t* __restrict__ w1T, bf16_t* __restrict__ w2T,
    const float* __restrict__ Wh, bf16_t* __restrict__ headT) {
    int bid = blockIdx.x;
    if (bid >= 4096) {                    // head conversion (layer 7 only)
        int b2 = bid - 4096;
        int tn = b2 % 500, tk = b2 / 500;
        wtr_tile(Wh, headT, C_DIM, V_DIM, tn * 64, tk * 64, threadIdx.x);
        return;
    }
    if (bid >= 1024) {
        int b = bid - 1024;
        const float* in; bf16_t* o2; int K, N, tn, tk;
        if (b < 1024) {
            int which = b >> 8, t = b & 255;
            in = which == 0 ? Wq : which == 1 ? Wk : which == 2 ? Wv : Wp;
            o2 = which < 3 ? qkvT + (size_t)which * C_DIM * C_DIM : projT;
            K = C_DIM; N = C_DIM; tn = t & 15; tk = t >> 4;
        } else if (b < 2048) {
            int t = b - 1024; in = W1; o2 = w1T;
            K = C_DIM; N = 4 * C_DIM; tn = t & 63; tk = t >> 6;
        } else {
            int t = b - 2048; in = W2; o2 = w2T;
            K = 4 * C_DIM; N = C_DIM; tn = t & 15; tk = t >> 4;
        }
        wtr_tile(in, o2, K, N, tn * 64, tk * 64, threadIdx.x);
        return;
    }
    int wave = threadIdx.x >> 6, lane = threadIdx.x & 63;
    int row  = bid * 4 + wave;
    const float* xr = x + (size_t)row * C_DIM;
    float4 v[4];
    float s = 0.f, sq = 0.f;
#pragma unroll
    for (int i = 0; i < 4; ++i) {
        v[i] = *(const float4*)(xr + i * 256 + lane * 4);
        s  += v[i].x + v[i].y + v[i].z + v[i].w;
        sq += v[i].x * v[i].x + v[i].y * v[i].y + v[i].z * v[i].z + v[i].w * v[i].w;
    }
#pragma unroll
    for (int m = 1; m < 64; m <<= 1) {
        s  += __shfl_xor(s, m);
        sq += __shfl_xor(sq, m);
    }
    float mu  = s * (1.f / 1024.f);
    float var = sq * (1.f / 1024.f) - mu * mu;
    float rs  = rsqrtf(var + 1e-5f);
    bf16_t* orow = out + (size_t)row * C_DIM;
#pragma unroll
    for (int i = 0; i < 4; ++i) {
        int c = i * 256 + lane * 4;
        float4 g4 = *(const float4*)(gam + c);
        float4 b4 = *(const float4*)(bet + c);
        bf16x4 o;
        o[0] = (bf16_t)((v[i].x - mu) * rs * g4.x + b4.x);
        o[1] = (bf16_t)((v[i].y - mu) * rs * g4.y + b4.y);
        o[2] = (bf16_t)((v[i].z - mu) * rs * g4.z + b4.z);
        o[3] = (bf16_t)((v[i].w - mu) * rs * g4.w + b4.w);
        *(bf16x4*)(orow + c) = o;
    }
}

// ---------------------------------------------------------------------------
// LayerNorm fp32 -> bf16 (standalone).  One wave per row.
// ---------------------------------------------------------------------------
__global__ __launch_bounds__(256) void ln_kernel(
    const float* __restrict__ x, const float* __restrict__ gam,
    const float* __restrict__ bet, bf16_t* __restrict__ out) {
    int wave = threadIdx.x >> 6, lane = threadIdx.x & 63;
    int row  = blockIdx.x * 4 + wave;
    const float* xr = x + (size_t)row * C_DIM;
    float4 v[4];
    float s = 0.f, sq = 0.f;
#pragma unroll
    for (int i = 0; i < 4; ++i) {
        v[i] = *(const float4*)(xr + i * 256 + lane * 4);
        s  += v[i].x + v[i].y + v[i].z + v[i].w;
        sq += v[i].x * v[i].x + v[i].y * v[i].y + v[i].z * v[i].z + v[i].w * v[i].w;
    }
#pragma unroll
    for (int m = 1; m < 64; m <<= 1) {
        s  += __shfl_xor(s, m);
        sq += __shfl_xor(sq, m);
    }
    float mu  = s * (1.f / 1024.f);
    float var = sq * (1.f / 1024.f) - mu * mu;
    float rs  = rsqrtf(var + 1e-5f);
    bf16_t* orow = out + (size_t)row * C_DIM;
#pragma unroll
    for (int i = 0; i < 4; ++i) {
        int c = i * 256 + lane * 4;
        float4 g4 = *(const float4*)(gam + c);
        float4 b4 = *(const float4*)(bet + c);
        bf16x4 o;
        o[0] = (bf16_t)((v[i].x - mu) * rs * g4.x + b4.x);
        o[1] = (bf16_t)((v[i].y - mu) * rs * g4.y + b4.y);
        o[2] = (bf16_t)((v[i].z - mu) * rs * g4.z + b4.z);
        o[3] = (bf16_t)((v[i].w - mu) * rs * g4.w + b4.w);
        *(bf16x4*)(orow + c) = o;
    }
}

// ---------------------------------------------------------------------------
// GEMM 128x128 (m97 structure + T2 swizzle) — for N-narrow GEMMs.
// KS = K-splits (grid = MT*NT*KS blocks): each split computes K/KS and
// commits via f32 atomicAdd (MODE 2); bias added only by split 0.
// MODE 0: store bf16   1: bf16 relu(+bias)   2: f32 atomic += (+bias)
// ---------------------------------------------------------------------------
template <int MODE>
__global__ __launch_bounds__(256) void gemm_kernel(
    const bf16_t* __restrict__ A, const bf16_t* __restrict__ Bt,
    const float* __restrict__ bias, void* __restrict__ Cout,
    int M, int N, int K, int KS) {
    __shared__ bf16_t Asm[2][128 * 32];
    __shared__ bf16_t Bsm[2][128 * 32];

    const int tid  = threadIdx.x;
    const int nwg  = gridDim.x;
    int bid = blockIdx.x;
    if ((nwg & 7) == 0) {
        int cpx = nwg >> 3;
        bid = (bid & 7) * cpx + (bid >> 3);
    }
    const int MT = M >> 7;
    const int nblk = MT * (N >> 7);
    const int kp = bid / nblk;
    bid %= nblk;
    const int mt = bid % MT, nt = bid / MT;
    const int mbase = mt << 7, nbase = nt << 7;
    const int wave = tid >> 6, lane = tid & 63;
    const int lr = lane & 15, lg = lane >> 4;
    const int wm = wave >> 1, wn = wave & 1;
    const int KL = K / KS;           // this split's K length
    const int koff = kp * KL;
    const int NK = KL >> 5;

    const int srow = lane >> 2;
    const int ssw  = (((lane & 3) ^ ((lane >> 3) & 3)) << 3);
    const bf16_t* aRow = A  + (size_t)(mbase + wave * 32 + srow) * K + koff + ssw;
    const bf16_t* bRow = Bt + (size_t)(nbase + wave * 32 + srow) * K + koff + ssw;
    const int ldsW = wave * 1024;

#define STAGE(buf, kt)                                                        \
    do {                                                                      \
        const bf16_t* ag = aRow + (size_t)(kt) * 32;                          \
        const bf16_t* bg = bRow + (size_t)(kt) * 32;                          \
        gl_lds16(ag,            &Asm[buf][ldsW]);                             \
        gl_lds16(ag + 16 * K,   &Asm[buf][ldsW + 512]);                       \
        gl_lds16(bg,            &Bsm[buf][ldsW]);                             \
        gl_lds16(bg + 16 * K,   &Bsm[buf][ldsW + 512]);                       \
    } while (0)

    STAGE(0, 0);
    __syncthreads();

    f32x4 acc[4][4] = {};
    const int rsw = ((lg ^ ((lr >> 1) & 3)) << 3);
    int buf = 0;
    for (int kt = 0; kt < NK; ++kt) {
        if (kt + 1 < NK) STAGE(buf ^ 1, kt + 1);
        bf16x8 af[4], bfr[4];
#pragma unroll
        for (int i = 0; i < 4; ++i)
            af[i] = *(const bf16x8*)&Asm[buf][(wm * 64 + i * 16 + lr) * 32 + rsw];
#pragma unroll
        for (int j = 0; j < 4; ++j)
            bfr[j] = *(const bf16x8*)&Bsm[buf][(wn * 64 + j * 16 + lr) * 32 + rsw];
#pragma unroll
        for (int i = 0; i < 4; ++i)
#pragma unroll
            for (int j = 0; j < 4; ++j)
                acc[i][j] = mfma16(af[i], bfr[j], acc[i][j]);
        __syncthreads();
        buf ^= 1;
    }
#undef STAGE

    float bj[4];
#pragma unroll
    for (int j = 0; j < 4; ++j)
        bj[j] = (bias && kp == 0) ? bias[nbase + wn * 64 + j * 16 + lr] : 0.0f;
#pragma unroll
    for (int i = 0; i < 4; ++i) {
#pragma unroll
        for (int j = 0; j < 4; ++j) {
            int col = nbase + wn * 64 + j * 16 + lr;
#pragma unroll
            for (int e = 0; e < 4; ++e) {
                int row = mbase + wm * 64 + i * 16 + lg * 4 + e;
                float val = acc[i][j][e] + bj[j];
                size_t off = (size_t)row * N + col;
                if (MODE == 0) {
                    ((bf16_t*)Cout)[off] = (bf16_t)val;
                } else if (MODE == 1) {
                    ((bf16_t*)Cout)[off] = (bf16_t)fmaxf(val, 0.0f);
                } else {
                    atomicAdd(&((float*)Cout)[off], val);
                }
            }
        }
    }
}

// ---------------------------------------------------------------------------
// GEMM 128x256, BK=32, 8 waves (2M x 4N), 64x64 per wave, 48 KiB LDS dbuf.
// __launch_bounds__(512,4): low VGPR -> 2 blocks/CU, cross-block overlap.
// HW-proven swizzle sw(r) = (r>>1)&3 (measured 0 conflicts).
// MODE 3: full-line epilogue (per-wave LDS transpose -> f32x4 NT stores).
// MODE 0: store bf16   1: bf16 relu(+bias)   3: store f32 nt
// ---------------------------------------------------------------------------
template <int MODE>
__global__ __launch_bounds__(512, 4) void gemmW_kernel(
    const bf16_t* __restrict__ A, const bf16_t* __restrict__ Bt,
    const float* __restrict__ bias, void* __restrict__ Cout,
    int M, int N, int K) {
    __shared__ __align__(16) char smem[49152];
    bf16_t (*As)[128 * 32] = (bf16_t(*)[128 * 32])smem;           // 16 KB
    bf16_t (*Bs)[256 * 32] = (bf16_t(*)[256 * 32])(smem + 16384); // 32 KB

    const int tid  = threadIdx.x;
    const int nwg  = gridDim.x;
    int bid = blockIdx.x;
    if ((nwg & 7) == 0) {
        int cpx = nwg >> 3;
        bid = (bid & 7) * cpx + (bid >> 3);
    }
    const int MT = M >> 7;
    const int mt = bid % MT, nt = bid / MT;
    const int mbase = mt << 7, nbase = nt << 8;
    const int wave = tid >> 6, lane = tid & 63;
    const int lr = lane & 15, lg = lane >> 4;
    const int wm64 = (wave >> 2) * 64;   // M half
    const int wn64 = (wave & 3) * 64;    // N quarter
    const int NK = K >> 5;

    const int srow = tid >> 2;
    const int csrc = (((tid & 3) ^ ((tid >> 3) & 3)) << 3);
    const bf16_t* aPtr = A  + (size_t)(mbase + srow) * K + csrc;
    const bf16_t* b0   = Bt + (size_t)(nbase + srow) * K + csrc;
    const bf16_t* b1   = b0 + (size_t)128 * K;   // sw(r+128)==sw(r)
    const int ldsW = wave * 512;

#define STAGEW(buf, kt)                                                       \
    do {                                                                      \
        gl_lds16(aPtr + (size_t)(kt) * 32, &As[buf][ldsW]);                   \
        gl_lds16(b0   + (size_t)(kt) * 32, &Bs[buf][ldsW]);                   \
        gl_lds16(b1   + (size_t)(kt) * 32, &Bs[buf][4096 + ldsW]);            \
    } while (0)

    STAGEW(0, 0);
    __syncthreads();

    f32x4 acc[4][4] = {};
    const int rofs = ((lg ^ ((lr >> 1) & 3)) << 3);
    int buf = 0;
    for (int kt = 0; kt < NK; ++kt) {
        if (kt + 1 < NK) STAGEW(buf ^ 1, kt + 1);
        bf16x8 af[4], bfr[4];
#pragma unroll
        for (int i = 0; i < 4; ++i)
            af[i] = *(const bf16x8*)&As[buf][(wm64 + i * 16 + lr) * 32 + rofs];
#pragma unroll
        for (int j = 0; j < 4; ++j)
            bfr[j] = *(const bf16x8*)&Bs[buf][(wn64 + j * 16 + lr) * 32 + rofs];
#pragma unroll
        for (int i = 0; i < 4; ++i)
#pragma unroll
            for (int j = 0; j < 4; ++j)
                acc[i][j] = mfma16(af[i], bfr[j], acc[i][j]);
        __syncthreads();
        buf ^= 1;
    }
#undef STAGEW

    float bj[4];
#pragma unroll
    for (int j = 0; j < 4; ++j)
        bj[j] = bias ? bias[nbase + wn64 + j * 16 + lr] : 0.0f;

    if (MODE == 3) {
        // full-line epilogue: per-wave private LDS slice [16][68] fp32.
        float* tw = (float*)smem + wave * (16 * 68);
#pragma unroll
        for (int i = 0; i < 4; ++i) {
#pragma unroll
            for (int j = 0; j < 4; ++j)
#pragma unroll
                for (int e = 0; e < 4; ++e)
                    tw[(lg * 4 + e) * 68 + j * 16 + lr] = acc[i][j][e] + bj[j];
            asm volatile("s_waitcnt lgkmcnt(0)" ::: "memory");
#pragma unroll
            for (int ss = 0; ss < 4; ++ss) {
                int rr = ss * 4 + lg;
                f32x4 v = *(const f32x4*)&tw[rr * 68 + lr * 4];
                size_t off = (size_t)(mbase + wm64 + i * 16 + rr) * N
                           + (nbase + wn64 + lr * 4);
                __builtin_nontemporal_store(v, (f32x4*)&((float*)Cout)[off]);
            }
            asm volatile("s_waitcnt lgkmcnt(0)" ::: "memory");
        }
        return;
    }

#pragma unroll
    for (int i = 0; i < 4; ++i) {
#pragma unroll
        for (int j = 0; j < 4; ++j) {
            int col = nbase + wn64 + j * 16 + lr;
#pragma unroll
            for (int e = 0; e < 4; ++e) {
                int row = mbase + wm64 + i * 16 + lg * 4 + e;
                float val = acc[i][j][e] + bj[j];
                size_t off = (size_t)row * N + col;
                if (MODE == 0) {
                    ((bf16_t*)Cout)[off] = (bf16_t)val;
                } else {
                    ((bf16_t*)Cout)[off] = (bf16_t)fmaxf(val, 0.0f);
                }
            }
        }
    }
}

// ---------------------------------------------------------------------------
// Flash attention (causal), NON-SPLIT, FIXED-MAX softmax.
// 512 blocks (qt,bh), LPT heavy-first; direct normalized bf16 output.
// ---------------------------------------------------------------------------
__global__ __launch_bounds__(256) void attn_kernel(
    const bf16_t* __restrict__ Qb, const bf16_t* __restrict__ Kb,
    const bf16_t* __restrict__ Vb, bf16_t* __restrict__ Ob) {
    __shared__ bf16_t Ksm[2][64][72];    // [key][d]
    __shared__ bf16_t Vsm[2][64][72];    // [d][key] (transposed)
    __shared__ bf16_t Psm[4][32][72];    // per-wave P [q][key]

    const int tid  = threadIdx.x;
    const int bid  = blockIdx.x;
    const int qt   = 7 - (bid >> 6);     // LPT: heaviest first
    const int bh   = bid & 63;
    const int hh   = bh & 15;
    const int bb   = bh >> 4;
    const int nkt  = 2 * qt + 2;
    const int wave = tid >> 6, lane = tid & 63;
    const int lr = lane & 15, lg = lane >> 4;
    const int qbase = qt * 128 + wave * 32;
    const size_t basei = ((size_t)bb * T_DIM) * LDQ + hh * HS;
    const size_t baseo = ((size_t)bb * T_DIM) * C_DIM + hh * HS;

    bf16x8 qf[2][2];
#pragma unroll
    for (int rb = 0; rb < 2; ++rb) {
        const bf16_t* qrow = Qb + basei + (size_t)(qbase + rb * 16 + lr) * LDQ;
        qf[rb][0] = *(const bf16x8*)(qrow + lg * 8);
        qf[rb][1] = *(const bf16x8*)(qrow + 32 + lg * 8);
    }

    f32x4 o[2][4] = {};
    float psum[2][4];
#pragma unroll
    for (int rb = 0; rb < 2; ++rb)
#pragma unroll
        for (int e = 0; e < 4; ++e) psum[rb][e] = 0.f;

    const int krow = tid >> 2, kc = (tid & 3) * 8;
    const bf16_t* kgp = Kb + basei + (size_t)krow * LDQ + kc;
    const int vds = (tid & 7) * 8, vkg = (tid >> 3) * 2;
    const bf16_t* vgp0 = Vb + basei + (size_t)vkg * LDQ + vds;
    const bf16_t* vgp1 = vgp0 + LDQ;

    uint4 k0r, k1r, v0r, v1r;
    k0r = *(const uint4*)(kgp);
    k1r = *(const uint4*)(kgp + 32);
    v0r = *(const uint4*)(vgp0);
    v1r = *(const uint4*)(vgp1);
    *(uint4*)&Ksm[0][krow][kc]      = k0r;
    *(uint4*)&Ksm[0][krow][kc + 32] = k1r;
    {
        const u16* e0 = (const u16*)&v0r;
        const u16* e1 = (const u16*)&v1r;
#pragma unroll
        for (int j = 0; j < 8; ++j)
            *(u32*)&Vsm[0][vds + j][vkg] = (u32)e0[j] | ((u32)e1[j] << 16);
    }
    __syncthreads();

    const float SCL = 0.18033688011112042f;   // 0.125 * log2(e)
    for (int kt = 0; kt < nkt; ++kt) {
        const int c = kt & 1;
        if (kt + 1 < nkt) {
            const size_t go = (size_t)(kt + 1) * 64 * LDQ;
            k0r = *(const uint4*)(kgp + go);
            k1r = *(const uint4*)(kgp + go + 32);
            v0r = *(const uint4*)(vgp0 + go);
            v1r = *(const uint4*)(vgp1 + go);
        }

        f32x4 s[2][4];
        __builtin_amdgcn_s_setprio(1);
#pragma unroll
        for (int kk = 0; kk < 4; ++kk) {
            bf16x8 kf0 = *(const bf16x8*)&Ksm[c][kk * 16 + lr][lg * 8];
            bf16x8 kf1 = *(const bf16x8*)&Ksm[c][kk * 16 + lr][32 + lg * 8];
#pragma unroll
            for (int rb = 0; rb < 2; ++rb) {
                f32x4 z = {};
                z = mfma16(qf[rb][0], kf0, z);
                z = mfma16(qf[rb][1], kf1, z);
                s[rb][kk] = z;
            }
        }
        __builtin_amdgcn_s_setprio(0);
        if (kt * 64 + 63 > qbase) {
#pragma unroll
            for (int rb = 0; rb < 2; ++rb)
#pragma unroll
                for (int kk = 0; kk < 4; ++kk)
#pragma unroll
                    for (int e = 0; e < 4; ++e) {
                        int key = kt * 64 + kk * 16 + lr;
                        int qi  = qbase + rb * 16 + lg * 4 + e;
                        float v = s[rb][kk][e] * SCL;
                        s[rb][kk][e] = (key <= qi) ? v : -1e30f;
                    }
        } else {
#pragma unroll
            for (int rb = 0; rb < 2; ++rb)
#pragma unroll
                for (int kk = 0; kk < 4; ++kk)
#pragma unroll
                    for (int e = 0; e < 4; ++e)
                        s[rb][kk][e] *= SCL;
        }

        // fixed-max softmax: p = exp2(s_scaled); masked -> 0
#pragma unroll
        for (int rb = 0; rb < 2; ++rb) {
#pragma unroll
            for (int e = 0; e < 4; ++e) {
                float p0 = exp2f(s[rb][0][e]);
                float p1 = exp2f(s[rb][1][e]);
                float p2 = exp2f(s[rb][2][e]);
                float p3 = exp2f(s[rb][3][e]);
                int qrow = rb * 16 + lg * 4 + e;
                Psm[wave][qrow][lr]      = (bf16_t)p0;
                Psm[wave][qrow][16 + lr] = (bf16_t)p1;
                Psm[wave][qrow][32 + lr] = (bf16_t)p2;
                Psm[wave][qrow][48 + lr] = (bf16_t)p3;
                psum[rb][e] += (p0 + p1) + (p2 + p3);
            }
        }

        asm volatile("s_waitcnt lgkmcnt(0)" ::: "memory");
        bf16x8 pf[2][2];
#pragma unroll
        for (int rb = 0; rb < 2; ++rb)
#pragma unroll
            for (int h2 = 0; h2 < 2; ++h2)
                pf[rb][h2] = *(const bf16x8*)&Psm[wave][rb * 16 + lr][h2 * 32 + lg * 8];
        __builtin_amdgcn_s_setprio(1);
#pragma unroll
        for (int h2 = 0; h2 < 2; ++h2)
#pragma unroll
            for (int db = 0; db < 4; ++db) {
                bf16x8 vf = *(const bf16x8*)&Vsm[c][db * 16 + lr][h2 * 32 + lg * 8];
#pragma unroll
                for (int rb = 0; rb < 2; ++rb)
                    o[rb][db] = mfma16(pf[rb][h2], vf, o[rb][db]);
            }
        __builtin_amdgcn_s_setprio(0);

        if (kt + 1 < nkt) {
            const int w = c ^ 1;
            *(uint4*)&Ksm[w][krow][kc]      = k0r;
            *(uint4*)&Ksm[w][krow][kc + 32] = k1r;
            const u16* e0 = (const u16*)&v0r;
            const u16* e1 = (const u16*)&v1r;
#pragma unroll
            for (int j = 0; j < 8; ++j)
                *(u32*)&Vsm[w][vds + j][vkg] = (u32)e0[j] | ((u32)e1[j] << 16);
        }
        __syncthreads();
    }

    // epilogue: normalize and store bf16 directly
#pragma unroll
    for (int rb = 0; rb < 2; ++rb)
#pragma unroll
        for (int e = 0; e < 4; ++e) {
            float l = psum[rb][e];
            l += __shfl_xor(l, 1);
            l += __shfl_xor(l, 2);
            l += __shfl_xor(l, 4);
            l += __shfl_xor(l, 8);
            float inv = 1.0f / l;
            bf16_t* orow = Ob + baseo + (size_t)(qbase + rb * 16 + lg * 4 + e) * C_DIM;
#pragma unroll
            for (int db = 0; db < 4; ++db)
                orow[db * 16 + lr] = (bf16_t)(o[rb][db][e] * inv);
        }
}

// ---------------------------------------------------------------------------
// Host launcher
// ---------------------------------------------------------------------------
extern "C" void kernel_launch(void* const* d_in, const int* in_sizes, int n_in,
                              void* d_out, int out_size, void* d_ws, size_t ws_size,
                              hipStream_t stream) {
    const int*   x      = (const int*)d_in[0];
    const float* tok    = (const float*)d_in[1];
    const float* pos    = (const float*)d_in[2];
    const float* Wq     = (const float*)d_in[3];
    const float* Wk     = (const float*)d_in[4];
    const float* Wv     = (const float*)d_in[5];
    const float* Wproj  = (const float*)d_in[6];
    const float* bproj  = (const float*)d_in[7];
    const float* ln1_g  = (const float*)d_in[8];
    const float* ln1_b  = (const float*)d_in[9];
    const float* ln2_g  = (const float*)d_in[10];
    const float* ln2_b  = (const float*)d_in[11];
    const float* W1     = (const float*)d_in[12];
    const float* b1     = (const float*)d_in[13];
    const float* W2     = (const float*)d_in[14];
    const float* b2     = (const float*)d_in[15];
    const float* lnf_g  = (const float*)d_in[16];
    const float* lnf_b  = (const float*)d_in[17];
    const float* Whead  = (const float*)d_in[18];
    float* out = (float*)d_out;

    char* ws = (char*)d_ws;
    float*  h    = (float*)ws;   ws += (size_t)NROWS * C_DIM * 4;          // 16 MB
    bf16_t* xn   = (bf16_t*)ws;  ws += (size_t)NROWS * C_DIM * 2;          // 8 MB
    bf16_t* qkvb = (bf16_t*)ws;  ws += (size_t)NROWS * LDQ * 2;            // 24 MB
    bf16_t* ob   = (bf16_t*)ws;  ws += (size_t)NROWS * C_DIM * 2;          // 8 MB
    bf16_t* mid  = (bf16_t*)ws;  ws += (size_t)NROWS * 4 * C_DIM * 2;      // 32 MB
    bf16_t* wT   = (bf16_t*)ws;  ws += (size_t)V_DIM * C_DIM * 2;          // 65.5 MB
    bf16_t* headT = (bf16_t*)ws; ws += (size_t)V_DIM * C_DIM * 2;          // 65.5 MB

    const size_t M1 = (size_t)C_DIM * C_DIM;
    bf16_t* qkvT  = wT;
    bf16_t* projT = wT + 3 * M1;
    bf16_t* w1T   = wT + 4 * M1;
    bf16_t* w2T   = wT + 8 * M1;

    dim3 blk(256);
    dim3 blk512(512);

    embed_kernel<<<dim3(NROWS * C_DIM / 1024), blk, 0, stream>>>(x, tok, pos, h);

    for (int l = 0; l < L_DIM; ++l) {
        const size_t wo  = (size_t)l * M1;
        const size_t wo1 = (size_t)l * 4 * M1;

        // fused LN1 + per-layer weight conversion (+ head conversion at l=7)
        int extra = (l == 7) ? 8000 : 0;
        ln_wtr_kernel<<<dim3(1024 + 3072 + extra), blk, 0, stream>>>(
            h, ln1_g + l * C_DIM, ln1_b + l * C_DIM, xn,
            Wq + wo, Wk + wo, Wv + wo, Wproj + wo, W1 + wo1, W2 + wo1,
            qkvT, projT, w1T, w2T, Whead, headT);

        // QKV on gemmW (grid 32*12 = 384 blocks)
        gemmW_kernel<0><<<dim3(32 * 12), blk512, 0, stream>>>(
            xn, qkvT, nullptr, qkvb, NROWS, LDQ, C_DIM);

        // non-split attention (512 blocks, LPT heavy-first), direct output
        attn_kernel<<<dim3(512), blk, 0, stream>>>(
            qkvb, qkvb + C_DIM, qkvb + 2 * C_DIM, ob);

        // proj: split-K=2 atomic (512 blocks, 2 blocks/CU)
        gemm_kernel<2><<<dim3(32 * 8 * 2), blk, 0, stream>>>(
            ob, projT, bproj + l * C_DIM, h, NROWS, C_DIM, C_DIM, 2);

        ln_kernel<<<dim3(NROWS / 4), blk, 0, stream>>>(h, ln2_g + l * C_DIM, ln2_b + l * C_DIM, xn);

        // MLP1 on gemmW (grid 32*16 = 512 blocks)
        gemmW_kernel<1><<<dim3(32 * 16), blk512, 0, stream>>>(
            xn, w1T, b1 + (size_t)l * 4 * C_DIM, mid, NROWS, 4 * C_DIM, C_DIM);

        // MLP2: split-K=2 atomic (512 blocks)
        gemm_kernel<2><<<dim3(32 * 8 * 2), blk, 0, stream>>>(
            mid, w2T, b2 + l * C_DIM, h, NROWS, C_DIM, 4 * C_DIM, 2);
    }

    ln_kernel<<<dim3(NROWS / 4), blk, 0, stream>>>(h, lnf_g, lnf_b, xn);
    // head on gemmW (grid 32*125 = 4000 blocks), weights pre-converted at l=7
    gemmW_kernel<3><<<dim3(32 * 125), blk512, 0, stream>>>(
        xn, headT, nullptr, out, NROWS, V_DIM, C_DIM);
}

// Round 21
// 2273.678 us; speedup vs baseline: 1.0030x; 1.0030x over previous
//
#include <hip/hip_runtime.h>
#include <stdint.h>
#include <stddef.h>

#define C_DIM 1024
#define T_DIM 1024
#define B_DIM 4
#define L_DIM 8
#define V_DIM 32000
#define HS 64
#define NHEAD 16
#define NROWS (B_DIM * T_DIM)   // 4096
#define LDQ   3072              // packed qkv row stride

typedef __bf16 bf16_t;
typedef __attribute__((ext_vector_type(8))) __bf16 bf16x8;
typedef __attribute__((ext_vector_type(4))) __bf16 bf16x4;
typedef __attribute__((ext_vector_type(4))) float f32x4;
typedef unsigned int u32;
typedef unsigned short u16;

static __device__ __forceinline__ f32x4 mfma16(bf16x8 a, bf16x8 b, f32x4 c) {
    return __builtin_amdgcn_mfma_f32_16x16x32_bf16(a, b, c, 0, 0, 0);
}

// async global->LDS, 16B per lane. LDS dest must be wave-uniform.
static __device__ __forceinline__ void gl_lds16(const bf16_t* g, bf16_t* l) {
    __builtin_amdgcn_global_load_lds(
        (const __attribute__((address_space(1))) u32*)(const void*)g,
        (__attribute__((address_space(3))) u32*)(void*)l, 16, 0, 0);
}

// ---------------------------------------------------------------------------
// Embedding
// ---------------------------------------------------------------------------
__global__ __launch_bounds__(256) void embed_kernel(
    const int* __restrict__ x, const float* __restrict__ tok,
    const float* __restrict__ pos, float* __restrict__ h) {
    int idx = blockIdx.x * 256 + threadIdx.x;
    int row = idx >> 8;
    int c4  = (idx & 255) * 4;
    int t   = row & (T_DIM - 1);
    int tk  = x[row];
    float4 a = *(const float4*)(tok + (size_t)tk * C_DIM + c4);
    float4 p = *(const float4*)(pos + (size_t)t * C_DIM + c4);
    float4 r;
    r.x = a.x + p.x; r.y = a.y + p.y; r.z = a.z + p.z; r.w = a.w + p.w;
    *(float4*)(h + (size_t)row * C_DIM + c4) = r;
}

// ---------------------------------------------------------------------------
// Weight convert+transpose 64x64 tile body:  f32 [K][N] -> bf16 [N][K]
// ---------------------------------------------------------------------------
static __device__ __forceinline__ void wtr_tile(
    const float* __restrict__ in, bf16_t* __restrict__ out,
    int K, int N, int n0, int k0, int tid) {
    __shared__ float t[64][65];
    int tx = tid & 63, tw = tid >> 6;
#pragma unroll 4
    for (int i = 0; i < 16; ++i) {
        int k = tw * 16 + i;
        t[k][tx] = in[(size_t)(k0 + k) * N + n0 + tx];
    }
    __syncthreads();
#pragma unroll 4
    for (int i = 0; i < 16; ++i) {
        int n = tw * 16 + i;
        out[(size_t)(n0 + n) * K + k0 + tx] = (bf16_t)t[tx][n];
    }
}

__global__ __launch_bounds__(256) void wtr_kernel(
    const float* __restrict__ in, bf16_t* __restrict__ out, int K, int N) {
    wtr_tile(in, out, K, N, blockIdx.x * 64, blockIdx.y * 64, threadIdx.x);
}

// ---------------------------------------------------------------------------
// Fused LayerNorm (blocks 0..1023) + per-layer weight conversion (1024..4095).
// ---------------------------------------------------------------------------
__global__ __launch_bounds__(256) void ln_wtr_kernel(
    const float* __restrict__ x, const float* __restrict__ gam,
    const float* __restrict__ bet, bf16_t* __restrict__ out,
    const float* __restrict__ Wq, const float* __restrict__ Wk,
    const float* __restrict__ Wv, const float* __restrict__ Wp,
    const float* __restrict__ W1, const float* __restrict__ W2,
    bf16_t* __restrict__ qkvT, bf16_t* __restrict__ projT,
    bf16_t* __restrict__ w1T, bf16_t* __restrict__ w2T) {
    int bid = blockIdx.x;
    if (bid >= 1024) {
        int b = bid - 1024;
        const float* in; bf16_t* o2; int K, N, tn, tk;
        if (b < 1024) {
            int which = b >> 8, t = b & 255;
            in = which == 0 ? Wq : which == 1 ? Wk : which == 2 ? Wv : Wp;
            o2 = which < 3 ? qkvT + (size_t)which * C_DIM * C_DIM : projT;
            K = C_DIM; N = C_DIM; tn = t & 15; tk = t >> 4;
        } else if (b < 2048) {
            int t = b - 1024; in = W1; o2 = w1T;
            K = C_DIM; N = 4 * C_DIM; tn = t & 63; tk = t >> 6;
        } else {
            int t = b - 2048; in = W2; o2 = w2T;
            K = 4 * C_DIM; N = C_DIM; tn = t & 15; tk = t >> 4;
        }
        wtr_tile(in, o2, K, N, tn * 64, tk * 64, threadIdx.x);
        return;
    }
    int wave = threadIdx.x >> 6, lane = threadIdx.x & 63;
    int row  = bid * 4 + wave;
    const float* xr = x + (size_t)row * C_DIM;
    float4 v[4];
    float s = 0.f, sq = 0.f;
#pragma unroll
    for (int i = 0; i < 4; ++i) {
        v[i] = *(const float4*)(xr + i * 256 + lane * 4);
        s  += v[i].x + v[i].y + v[i].z + v[i].w;
        sq += v[i].x * v[i].x + v[i].y * v[i].y + v[i].z * v[i].z + v[i].w * v[i].w;
    }
#pragma unroll
    for (int m = 1; m < 64; m <<= 1) {
        s  += __shfl_xor(s, m);
        sq += __shfl_xor(sq, m);
    }
    float mu  = s * (1.f / 1024.f);
    float var = sq * (1.f / 1024.f) - mu * mu;
    float rs  = rsqrtf(var + 1e-5f);
    bf16_t* orow = out + (size_t)row * C_DIM;
#pragma unroll
    for (int i = 0; i < 4; ++i) {
        int c = i * 256 + lane * 4;
        float4 g4 = *(const float4*)(gam + c);
        float4 b4 = *(const float4*)(bet + c);
        bf16x4 o;
        o[0] = (bf16_t)((v[i].x - mu) * rs * g4.x + b4.x);
        o[1] = (bf16_t)((v[i].y - mu) * rs * g4.y + b4.y);
        o[2] = (bf16_t)((v[i].z - mu) * rs * g4.z + b4.z);
        o[3] = (bf16_t)((v[i].w - mu) * rs * g4.w + b4.w);
        *(bf16x4*)(orow + c) = o;
    }
}

// ---------------------------------------------------------------------------
// LayerNorm fp32 -> bf16 (standalone).  One wave per row.
// ---------------------------------------------------------------------------
__global__ __launch_bounds__(256) void ln_kernel(
    const float* __restrict__ x, const float* __restrict__ gam,
    const float* __restrict__ bet, bf16_t* __restrict__ out) {
    int wave = threadIdx.x >> 6, lane = threadIdx.x & 63;
    int row  = blockIdx.x * 4 + wave;
    const float* xr = x + (size_t)row * C_DIM;
    float4 v[4];
    float s = 0.f, sq = 0.f;
#pragma unroll
    for (int i = 0; i < 4; ++i) {
        v[i] = *(const float4*)(xr + i * 256 + lane * 4);
        s  += v[i].x + v[i].y + v[i].z + v[i].w;
        sq += v[i].x * v[i].x + v[i].y * v[i].y + v[i].z * v[i].z + v[i].w * v[i].w;
    }
#pragma unroll
    for (int m = 1; m < 64; m <<= 1) {
        s  += __shfl_xor(s, m);
        sq += __shfl_xor(sq, m);
    }
    float mu  = s * (1.f / 1024.f);
    float var = sq * (1.f / 1024.f) - mu * mu;
    float rs  = rsqrtf(var + 1e-5f);
    bf16_t* orow = out + (size_t)row * C_DIM;
#pragma unroll
    for (int i = 0; i < 4; ++i) {
        int c = i * 256 + lane * 4;
        float4 g4 = *(const float4*)(gam + c);
        float4 b4 = *(const float4*)(bet + c);
        bf16x4 o;
        o[0] = (bf16_t)((v[i].x - mu) * rs * g4.x + b4.x);
        o[1] = (bf16_t)((v[i].y - mu) * rs * g4.y + b4.y);
        o[2] = (bf16_t)((v[i].z - mu) * rs * g4.z + b4.z);
        o[3] = (bf16_t)((v[i].w - mu) * rs * g4.w + b4.w);
        *(bf16x4*)(orow + c) = o;
    }
}

// ---------------------------------------------------------------------------
// GEMM 128x128 (m97 structure + T2 swizzle) — for N-narrow GEMMs.
// KS = K-splits (grid = MT*NT*KS blocks): each split computes K/KS and
// commits via f32 atomicAdd (MODE 2); bias added only by split 0.
// MODE 0: store bf16   1: bf16 relu(+bias)   2: f32 atomic += (+bias)
// ---------------------------------------------------------------------------
template <int MODE>
__global__ __launch_bounds__(256) void gemm_kernel(
    const bf16_t* __restrict__ A, const bf16_t* __restrict__ Bt,
    const float* __restrict__ bias, void* __restrict__ Cout,
    int M, int N, int K, int KS) {
    __shared__ bf16_t Asm[2][128 * 32];
    __shared__ bf16_t Bsm[2][128 * 32];

    const int tid  = threadIdx.x;
    const int nwg  = gridDim.x;
    int bid = blockIdx.x;
    if ((nwg & 7) == 0) {
        int cpx = nwg >> 3;
        bid = (bid & 7) * cpx + (bid >> 3);
    }
    const int MT = M >> 7;
    const int nblk = MT * (N >> 7);
    const int kp = bid / nblk;
    bid %= nblk;
    const int mt = bid % MT, nt = bid / MT;
    const int mbase = mt << 7, nbase = nt << 7;
    const int wave = tid >> 6, lane = tid & 63;
    const int lr = lane & 15, lg = lane >> 4;
    const int wm = wave >> 1, wn = wave & 1;
    const int KL = K / KS;           // this split's K length
    const int koff = kp * KL;
    const int NK = KL >> 5;

    const int srow = lane >> 2;
    const int ssw  = (((lane & 3) ^ ((lane >> 3) & 3)) << 3);
    const bf16_t* aRow = A  + (size_t)(mbase + wave * 32 + srow) * K + koff + ssw;
    const bf16_t* bRow = Bt + (size_t)(nbase + wave * 32 + srow) * K + koff + ssw;
    const int ldsW = wave * 1024;

#define STAGE(buf, kt)                                                        \
    do {                                                                      \
        const bf16_t* ag = aRow + (size_t)(kt) * 32;                          \
        const bf16_t* bg = bRow + (size_t)(kt) * 32;                          \
        gl_lds16(ag,            &Asm[buf][ldsW]);                             \
        gl_lds16(ag + 16 * K,   &Asm[buf][ldsW + 512]);                       \
        gl_lds16(bg,            &Bsm[buf][ldsW]);                             \
        gl_lds16(bg + 16 * K,   &Bsm[buf][ldsW + 512]);                       \
    } while (0)

    STAGE(0, 0);
    __syncthreads();

    f32x4 acc[4][4] = {};
    const int rsw = ((lg ^ ((lr >> 1) & 3)) << 3);
    int buf = 0;
    for (int kt = 0; kt < NK; ++kt) {
        if (kt + 1 < NK) STAGE(buf ^ 1, kt + 1);
        bf16x8 af[4], bfr[4];
#pragma unroll
        for (int i = 0; i < 4; ++i)
            af[i] = *(const bf16x8*)&Asm[buf][(wm * 64 + i * 16 + lr) * 32 + rsw];
#pragma unroll
        for (int j = 0; j < 4; ++j)
            bfr[j] = *(const bf16x8*)&Bsm[buf][(wn * 64 + j * 16 + lr) * 32 + rsw];
#pragma unroll
        for (int i = 0; i < 4; ++i)
#pragma unroll
            for (int j = 0; j < 4; ++j)
                acc[i][j] = mfma16(af[i], bfr[j], acc[i][j]);
        __syncthreads();
        buf ^= 1;
    }
#undef STAGE

    float bj[4];
#pragma unroll
    for (int j = 0; j < 4; ++j)
        bj[j] = (bias && kp == 0) ? bias[nbase + wn * 64 + j * 16 + lr] : 0.0f;
#pragma unroll
    for (int i = 0; i < 4; ++i) {
#pragma unroll
        for (int j = 0; j < 4; ++j) {
            int col = nbase + wn * 64 + j * 16 + lr;
#pragma unroll
            for (int e = 0; e < 4; ++e) {
                int row = mbase + wm * 64 + i * 16 + lg * 4 + e;
                float val = acc[i][j][e] + bj[j];
                size_t off = (size_t)row * N + col;
                if (MODE == 0) {
                    ((bf16_t*)Cout)[off] = (bf16_t)val;
                } else if (MODE == 1) {
                    ((bf16_t*)Cout)[off] = (bf16_t)fmaxf(val, 0.0f);
                } else {
                    atomicAdd(&((float*)Cout)[off], val);
                }
            }
        }
    }
}

// ---------------------------------------------------------------------------
// GEMM 128x256, BK=32, 8 waves (2M x 4N), 64x64 per wave, 48 KiB LDS dbuf.
// __launch_bounds__(512,4): low VGPR -> 2 blocks/CU, cross-block overlap.
// HW-proven swizzle sw(r) = (r>>1)&3 (measured 0 conflicts).
// MODE 3: full-line epilogue (per-wave LDS transpose -> f32x4 NT stores).
// MODE 0: store bf16   1: bf16 relu(+bias)   3: store f32 nt
// ---------------------------------------------------------------------------
template <int MODE>
__global__ __launch_bounds__(512, 4) void gemmW_kernel(
    const bf16_t* __restrict__ A, const bf16_t* __restrict__ Bt,
    const float* __restrict__ bias, void* __restrict__ Cout,
    int M, int N, int K) {
    __shared__ __align__(16) char smem[49152];
    bf16_t (*As)[128 * 32] = (bf16_t(*)[128 * 32])smem;           // 16 KB
    bf16_t (*Bs)[256 * 32] = (bf16_t(*)[256 * 32])(smem + 16384); // 32 KB

    const int tid  = threadIdx.x;
    const int nwg  = gridDim.x;
    int bid = blockIdx.x;
    if ((nwg & 7) == 0) {
        int cpx = nwg >> 3;
        bid = (bid & 7) * cpx + (bid >> 3);
    }
    const int MT = M >> 7;
    const int mt = bid % MT, nt = bid / MT;
    const int mbase = mt << 7, nbase = nt << 8;
    const int wave = tid >> 6, lane = tid & 63;
    const int lr = lane & 15, lg = lane >> 4;
    const int wm64 = (wave >> 2) * 64;   // M half
    const int wn64 = (wave & 3) * 64;    // N quarter
    const int NK = K >> 5;

    const int srow = tid >> 2;
    const int csrc = (((tid & 3) ^ ((tid >> 3) & 3)) << 3);
    const bf16_t* aPtr = A  + (size_t)(mbase + srow) * K + csrc;
    const bf16_t* b0   = Bt + (size_t)(nbase + srow) * K + csrc;
    const bf16_t* b1   = b0 + (size_t)128 * K;   // sw(r+128)==sw(r)
    const int ldsW = wave * 512;

#define STAGEW(buf, kt)                                                       \
    do {                                                                      \
        gl_lds16(aPtr + (size_t)(kt) * 32, &As[buf][ldsW]);                   \
        gl_lds16(b0   + (size_t)(kt) * 32, &Bs[buf][ldsW]);                   \
        gl_lds16(b1   + (size_t)(kt) * 32, &Bs[buf][4096 + ldsW]);            \
    } while (0)

    STAGEW(0, 0);
    __syncthreads();

    f32x4 acc[4][4] = {};
    const int rofs = ((lg ^ ((lr >> 1) & 3)) << 3);
    int buf = 0;
    for (int kt = 0; kt < NK; ++kt) {
        if (kt + 1 < NK) STAGEW(buf ^ 1, kt + 1);
        bf16x8 af[4], bfr[4];
#pragma unroll
        for (int i = 0; i < 4; ++i)
            af[i] = *(const bf16x8*)&As[buf][(wm64 + i * 16 + lr) * 32 + rofs];
#pragma unroll
        for (int j = 0; j < 4; ++j)
            bfr[j] = *(const bf16x8*)&Bs[buf][(wn64 + j * 16 + lr) * 32 + rofs];
#pragma unroll
        for (int i = 0; i < 4; ++i)
#pragma unroll
            for (int j = 0; j < 4; ++j)
                acc[i][j] = mfma16(af[i], bfr[j], acc[i][j]);
        __syncthreads();
        buf ^= 1;
    }
#undef STAGEW

    float bj[4];
#pragma unroll
    for (int j = 0; j < 4; ++j)
        bj[j] = bias ? bias[nbase + wn64 + j * 16 + lr] : 0.0f;

    if (MODE == 3) {
        // full-line epilogue: per-wave private LDS slice [16][68] fp32.
        float* tw = (float*)smem + wave * (16 * 68);
#pragma unroll
        for (int i = 0; i < 4; ++i) {
#pragma unroll
            for (int j = 0; j < 4; ++j)
#pragma unroll
                for (int e = 0; e < 4; ++e)
                    tw[(lg * 4 + e) * 68 + j * 16 + lr] = acc[i][j][e] + bj[j];
            asm volatile("s_waitcnt lgkmcnt(0)" ::: "memory");
#pragma unroll
            for (int ss = 0; ss < 4; ++ss) {
                int rr = ss * 4 + lg;
                f32x4 v = *(const f32x4*)&tw[rr * 68 + lr * 4];
                size_t off = (size_t)(mbase + wm64 + i * 16 + rr) * N
                           + (nbase + wn64 + lr * 4);
                __builtin_nontemporal_store(v, (f32x4*)&((float*)Cout)[off]);
            }
            asm volatile("s_waitcnt lgkmcnt(0)" ::: "memory");
        }
        return;
    }

#pragma unroll
    for (int i = 0; i < 4; ++i) {
#pragma unroll
        for (int j = 0; j < 4; ++j) {
            int col = nbase + wn64 + j * 16 + lr;
#pragma unroll
            for (int e = 0; e < 4; ++e) {
                int row = mbase + wm64 + i * 16 + lg * 4 + e;
                float val = acc[i][j][e] + bj[j];
                size_t off = (size_t)row * N + col;
                if (MODE == 0) {
                    ((bf16_t*)Cout)[off] = (bf16_t)val;
                } else {
                    ((bf16_t*)Cout)[off] = (bf16_t)fmaxf(val, 0.0f);
                }
            }
        }
    }
}

// ---------------------------------------------------------------------------
// Flash attention (causal), NON-SPLIT, FIXED-MAX softmax.
// 512 blocks (qt,bh), LPT heavy-first; direct normalized bf16 output.
// ---------------------------------------------------------------------------
__global__ __launch_bounds__(256) void attn_kernel(
    const bf16_t* __restrict__ Qb, const bf16_t* __restrict__ Kb,
    const bf16_t* __restrict__ Vb, bf16_t* __restrict__ Ob) {
    __shared__ bf16_t Ksm[2][64][72];    // [key][d]
    __shared__ bf16_t Vsm[2][64][72];    // [d][key] (transposed)
    __shared__ bf16_t Psm[4][32][72];    // per-wave P [q][key]

    const int tid  = threadIdx.x;
    const int bid  = blockIdx.x;
    const int qt   = 7 - (bid >> 6);     // LPT: heaviest first
    const int bh   = bid & 63;
    const int hh   = bh & 15;
    const int bb   = bh >> 4;
    const int nkt  = 2 * qt + 2;
    const int wave = tid >> 6, lane = tid & 63;
    const int lr = lane & 15, lg = lane >> 4;
    const int qbase = qt * 128 + wave * 32;
    const size_t basei = ((size_t)bb * T_DIM) * LDQ + hh * HS;
    const size_t baseo = ((size_t)bb * T_DIM) * C_DIM + hh * HS;

    bf16x8 qf[2][2];
#pragma unroll
    for (int rb = 0; rb < 2; ++rb) {
        const bf16_t* qrow = Qb + basei + (size_t)(qbase + rb * 16 + lr) * LDQ;
        qf[rb][0] = *(const bf16x8*)(qrow + lg * 8);
        qf[rb][1] = *(const bf16x8*)(qrow + 32 + lg * 8);
    }

    f32x4 o[2][4] = {};
    float psum[2][4];
#pragma unroll
    for (int rb = 0; rb < 2; ++rb)
#pragma unroll
        for (int e = 0; e < 4; ++e) psum[rb][e] = 0.f;

    const int krow = tid >> 2, kc = (tid & 3) * 8;
    const bf16_t* kgp = Kb + basei + (size_t)krow * LDQ + kc;
    const int vds = (tid & 7) * 8, vkg = (tid >> 3) * 2;
    const bf16_t* vgp0 = Vb + basei + (size_t)vkg * LDQ + vds;
    const bf16_t* vgp1 = vgp0 + LDQ;

    uint4 k0r, k1r, v0r, v1r;
    k0r = *(const uint4*)(kgp);
    k1r = *(const uint4*)(kgp + 32);
    v0r = *(const uint4*)(vgp0);
    v1r = *(const uint4*)(vgp1);
    *(uint4*)&Ksm[0][krow][kc]      = k0r;
    *(uint4*)&Ksm[0][krow][kc + 32] = k1r;
    {
        const u16* e0 = (const u16*)&v0r;
        const u16* e1 = (const u16*)&v1r;
#pragma unroll
        for (int j = 0; j < 8; ++j)
            *(u32*)&Vsm[0][vds + j][vkg] = (u32)e0[j] | ((u32)e1[j] << 16);
    }
    __syncthreads();

    const float SCL = 0.18033688011112042f;   // 0.125 * log2(e)
    for (int kt = 0; kt < nkt; ++kt) {
        const int c = kt & 1;
        if (kt + 1 < nkt) {
            const size_t go = (size_t)(kt + 1) * 64 * LDQ;
            k0r = *(const uint4*)(kgp + go);
            k1r = *(const uint4*)(kgp + go + 32);
            v0r = *(const uint4*)(vgp0 + go);
            v1r = *(const uint4*)(vgp1 + go);
        }

        f32x4 s[2][4];
        __builtin_amdgcn_s_setprio(1);
#pragma unroll
        for (int kk = 0; kk < 4; ++kk) {
            bf16x8 kf0 = *(const bf16x8*)&Ksm[c][kk * 16 + lr][lg * 8];
            bf16x8 kf1 = *(const bf16x8*)&Ksm[c][kk * 16 + lr][32 + lg * 8];
#pragma unroll
            for (int rb = 0; rb < 2; ++rb) {
                f32x4 z = {};
                z = mfma16(qf[rb][0], kf0, z);
                z = mfma16(qf[rb][1], kf1, z);
                s[rb][kk] = z;
            }
        }
        __builtin_amdgcn_s_setprio(0);
        if (kt * 64 + 63 > qbase) {
#pragma unroll
            for (int rb = 0; rb < 2; ++rb)
#pragma unroll
                for (int kk = 0; kk < 4; ++kk)
#pragma unroll
                    for (int e = 0; e < 4; ++e) {
                        int key = kt * 64 + kk * 16 + lr;
                        int qi  = qbase + rb * 16 + lg * 4 + e;
                        float v = s[rb][kk][e] * SCL;
                        s[rb][kk][e] = (key <= qi) ? v : -1e30f;
                    }
        } else {
#pragma unroll
            for (int rb = 0; rb < 2; ++rb)
#pragma unroll
                for (int kk = 0; kk < 4; ++kk)
#pragma unroll
                    for (int e = 0; e < 4; ++e)
                        s[rb][kk][e] *= SCL;
        }

        // fixed-max softmax: p = exp2(s_scaled); masked -> 0
#pragma unroll
        for (int rb = 0; rb < 2; ++rb) {
#pragma unroll
            for (int e = 0; e < 4; ++e) {
                float p0 = exp2f(s[rb][0][e]);
                float p1 = exp2f(s[rb][1][e]);
                float p2 = exp2f(s[rb][2][e]);
                float p3 = exp2f(s[rb][3][e]);
                int qrow = rb * 16 + lg * 4 + e;
                Psm[wave][qrow][lr]      = (bf16_t)p0;
                Psm[wave][qrow][16 + lr] = (bf16_t)p1;
                Psm[wave][qrow][32 + lr] = (bf16_t)p2;
                Psm[wave][qrow][48 + lr] = (bf16_t)p3;
                psum[rb][e] += (p0 + p1) + (p2 + p3);
            }
        }

        asm volatile("s_waitcnt lgkmcnt(0)" ::: "memory");
        bf16x8 pf[2][2];
#pragma unroll
        for (int rb = 0; rb < 2; ++rb)
#pragma unroll
            for (int h2 = 0; h2 < 2; ++h2)
                pf[rb][h2] = *(const bf16x8*)&Psm[wave][rb * 16 + lr][h2 * 32 + lg * 8];
        __builtin_amdgcn_s_setprio(1);
#pragma unroll
        for (int h2 = 0; h2 < 2; ++h2)
#pragma unroll
            for (int db = 0; db < 4; ++db) {
                bf16x8 vf = *(const bf16x8*)&Vsm[c][db * 16 + lr][h2 * 32 + lg * 8];
#pragma unroll
                for (int rb = 0; rb < 2; ++rb)
                    o[rb][db] = mfma16(pf[rb][h2], vf, o[rb][db]);
            }
        __builtin_amdgcn_s_setprio(0);

        if (kt + 1 < nkt) {
            const int w = c ^ 1;
            *(uint4*)&Ksm[w][krow][kc]      = k0r;
            *(uint4*)&Ksm[w][krow][kc + 32] = k1r;
            const u16* e0 = (const u16*)&v0r;
            const u16* e1 = (const u16*)&v1r;
#pragma unroll
            for (int j = 0; j < 8; ++j)
                *(u32*)&Vsm[w][vds + j][vkg] = (u32)e0[j] | ((u32)e1[j] << 16);
        }
        __syncthreads();
    }

    // epilogue: normalize and store bf16 directly
#pragma unroll
    for (int rb = 0; rb < 2; ++rb)
#pragma unroll
        for (int e = 0; e < 4; ++e) {
            float l = psum[rb][e];
            l += __shfl_xor(l, 1);
            l += __shfl_xor(l, 2);
            l += __shfl_xor(l, 4);
            l += __shfl_xor(l, 8);
            float inv = 1.0f / l;
            bf16_t* orow = Ob + baseo + (size_t)(qbase + rb * 16 + lg * 4 + e) * C_DIM;
#pragma unroll
            for (int db = 0; db < 4; ++db)
                orow[db * 16 + lr] = (bf16_t)(o[rb][db][e] * inv);
        }
}

// ---------------------------------------------------------------------------
// Host launcher
// ---------------------------------------------------------------------------
extern "C" void kernel_launch(void* const* d_in, const int* in_sizes, int n_in,
                              void* d_out, int out_size, void* d_ws, size_t ws_size,
                              hipStream_t stream) {
    const int*   x      = (const int*)d_in[0];
    const float* tok    = (const float*)d_in[1];
    const float* pos    = (const float*)d_in[2];
    const float* Wq     = (const float*)d_in[3];
    const float* Wk     = (const float*)d_in[4];
    const float* Wv     = (const float*)d_in[5];
    const float* Wproj  = (const float*)d_in[6];
    const float* bproj  = (const float*)d_in[7];
    const float* ln1_g  = (const float*)d_in[8];
    const float* ln1_b  = (const float*)d_in[9];
    const float* ln2_g  = (const float*)d_in[10];
    const float* ln2_b  = (const float*)d_in[11];
    const float* W1     = (const float*)d_in[12];
    const float* b1     = (const float*)d_in[13];
    const float* W2     = (const float*)d_in[14];
    const float* b2     = (const float*)d_in[15];
    const float* lnf_g  = (const float*)d_in[16];
    const float* lnf_b  = (const float*)d_in[17];
    const float* Whead  = (const float*)d_in[18];
    float* out = (float*)d_out;

    char* ws = (char*)d_ws;
    float*  h    = (float*)ws;   ws += (size_t)NROWS * C_DIM * 4;          // 16 MB
    bf16_t* xn   = (bf16_t*)ws;  ws += (size_t)NROWS * C_DIM * 2;          // 8 MB
    bf16_t* qkvb = (bf16_t*)ws;  ws += (size_t)NROWS * LDQ * 2;            // 24 MB
    bf16_t* ob   = (bf16_t*)ws;  ws += (size_t)NROWS * C_DIM * 2;          // 8 MB
    bf16_t* mid  = (bf16_t*)ws;  ws += (size_t)NROWS * 4 * C_DIM * 2;      // 32 MB
    bf16_t* wT   = (bf16_t*)ws;  ws += (size_t)V_DIM * C_DIM * 2;          // 65.5 MB

    const size_t M1 = (size_t)C_DIM * C_DIM;
    bf16_t* qkvT  = wT;
    bf16_t* projT = wT + 3 * M1;
    bf16_t* w1T   = wT + 4 * M1;
    bf16_t* w2T   = wT + 8 * M1;

    dim3 blk(256);
    dim3 blk512(512);

    embed_kernel<<<dim3(NROWS * C_DIM / 1024), blk, 0, stream>>>(x, tok, pos, h);

    for (int l = 0; l < L_DIM; ++l) {
        const size_t wo  = (size_t)l * M1;
        const size_t wo1 = (size_t)l * 4 * M1;

        // fused LN1 + per-layer weight conversion
        ln_wtr_kernel<<<dim3(1024 + 3072), blk, 0, stream>>>(
            h, ln1_g + l * C_DIM, ln1_b + l * C_DIM, xn,
            Wq + wo, Wk + wo, Wv + wo, Wproj + wo, W1 + wo1, W2 + wo1,
            qkvT, projT, w1T, w2T);

        // QKV on gemmW (grid 32*12 = 384 blocks)
        gemmW_kernel<0><<<dim3(32 * 12), blk512, 0, stream>>>(
            xn, qkvT, nullptr, qkvb, NROWS, LDQ, C_DIM);

        // non-split attention (512 blocks, LPT heavy-first), direct output
        attn_kernel<<<dim3(512), blk, 0, stream>>>(
            qkvb, qkvb + C_DIM, qkvb + 2 * C_DIM, ob);

        // proj: split-K=2 atomic (512 blocks, 2 blocks/CU)
        gemm_kernel<2><<<dim3(32 * 8 * 2), blk, 0, stream>>>(
            ob, projT, bproj + l * C_DIM, h, NROWS, C_DIM, C_DIM, 2);

        ln_kernel<<<dim3(NROWS / 4), blk, 0, stream>>>(h, ln2_g + l * C_DIM, ln2_b + l * C_DIM, xn);

        // MLP1 on gemmW (grid 32*16 = 512 blocks)
        gemmW_kernel<1><<<dim3(32 * 16), blk512, 0, stream>>>(
            xn, w1T, b1 + (size_t)l * 4 * C_DIM, mid, NROWS, 4 * C_DIM, C_DIM);

        // MLP2: split-K=2 atomic (512 blocks)
        gemm_kernel<2><<<dim3(32 * 8 * 2), blk, 0, stream>>>(
            mid, w2T, b2 + l * C_DIM, h, NROWS, C_DIM, 4 * C_DIM, 2);
    }

    ln_kernel<<<dim3(NROWS / 4), blk, 0, stream>>>(h, lnf_g, lnf_b, xn);
    wtr_kernel<<<dim3(500, 16), blk, 0, stream>>>(Whead, wT, C_DIM, V_DIM);
    // head on gemmW (grid 32*125 = 4000 blocks)
    gemmW_kernel<3><<<dim3(32 * 125), blk512, 0, stream>>>(
        xn, wT, nullptr, out, NROWS, V_DIM, C_DIM);
}